// Round 1
// baseline (139.145 us; speedup 1.0000x reference)
//
#include <hip/hip_runtime.h>

typedef __bf16 bf16;
typedef bf16 bf16x8 __attribute__((ext_vector_type(8)));
typedef bf16 bf16x4 __attribute__((ext_vector_type(4)));
typedef float f32x4 __attribute__((ext_vector_type(4)));

#define EPS 1e-5f
#define SLOPE 0.01f

// async global->LDS, 16B/lane. Invariant: lds ptr == wave-uniform base + lane*16B.
__device__ __forceinline__ void gld_lds16(const bf16* g, bf16* l) {
    __builtin_amdgcn_global_load_lds(
        (const __attribute__((address_space(1))) unsigned int*)g,
        (__attribute__((address_space(3))) unsigned int*)l, 16, 0, 0);
}

// ---------- prep: xT[b][l][c], xB[b][c][l], Wk/Wv/Wo bf16, WqT[h][c][e] ------
__global__ __launch_bounds__(256) void prep_kernel(
    const float* __restrict__ x,
    const float* __restrict__ Wq, const float* __restrict__ Wk,
    const float* __restrict__ Wv, const float* __restrict__ Wo,
    bf16* __restrict__ xT, bf16* __restrict__ xB,
    bf16* __restrict__ WkB, bf16* __restrict__ WvB,
    bf16* __restrict__ WoB, bf16* __restrict__ WqT)
{
    __shared__ float tile[64][65];
    const int id = blockIdx.x;
    const int t = threadIdx.x;
    if (id < 1024) {
        const int lt = id & 15, ct = (id >> 4) & 3, b = id >> 6;
        {
            const int cl = t >> 2;            // c within tile
            const int l4 = (t & 3) << 4;      // l within tile (16-chunks)
            const float* src = x + (size_t)(b * 256 + ct * 64 + cl) * 1024 + lt * 64 + l4;
            float4 v0 = ((const float4*)src)[0];
            float4 v1 = ((const float4*)src)[1];
            float4 v2 = ((const float4*)src)[2];
            float4 v3 = ((const float4*)src)[3];
            bf16x8 r0, r1;
            r0[0]=(bf16)v0.x; r0[1]=(bf16)v0.y; r0[2]=(bf16)v0.z; r0[3]=(bf16)v0.w;
            r0[4]=(bf16)v1.x; r0[5]=(bf16)v1.y; r0[6]=(bf16)v1.z; r0[7]=(bf16)v1.w;
            r1[0]=(bf16)v2.x; r1[1]=(bf16)v2.y; r1[2]=(bf16)v2.z; r1[3]=(bf16)v2.w;
            r1[4]=(bf16)v3.x; r1[5]=(bf16)v3.y; r1[6]=(bf16)v3.z; r1[7]=(bf16)v3.w;
            bf16* xbd = xB + (size_t)(b * 256 + ct * 64 + cl) * 1024 + lt * 64 + l4;
            *(bf16x8*)xbd = r0;
            *(bf16x8*)(xbd + 8) = r1;
            float* tr = &tile[cl][l4];
            tr[0]=v0.x; tr[1]=v0.y; tr[2]=v0.z; tr[3]=v0.w;
            tr[4]=v1.x; tr[5]=v1.y; tr[6]=v1.z; tr[7]=v1.w;
            tr[8]=v2.x; tr[9]=v2.y; tr[10]=v2.z; tr[11]=v2.w;
            tr[12]=v3.x; tr[13]=v3.y; tr[14]=v3.z; tr[15]=v3.w;
        }
        __syncthreads();
        {
            const int lw = t >> 2;            // l within tile
            const int ec = (t & 3) << 4;      // c within tile
            bf16x8 o0, o1;
            #pragma unroll
            for (int ii = 0; ii < 8; ++ii) {
                o0[ii] = (bf16)tile[ec + ii][lw];
                o1[ii] = (bf16)tile[ec + 8 + ii][lw];
            }
            bf16* dst = xT + (size_t)(b * 1024 + lt * 64 + lw) * 256 + ct * 64 + ec;
            *(bf16x8*)dst = o0;
            *(bf16x8*)(dst + 8) = o1;
        }
    } else if (id < 1408) {
        // straight bf16 casts of Wk, Wv, Wo
        const int i = (id - 1024) * 1024 + t * 4;    // [0, 393216)
        const float* src; bf16* dst;
        if (i < 131072)      { src = Wk + i;            dst = WkB + i; }
        else if (i < 262144) { src = Wv + (i - 131072); dst = WvB + (i - 131072); }
        else                 { src = Wo + (i - 262144); dst = WoB + (i - 262144); }
        float4 v = *(const float4*)src;
        bf16x4 o;
        o[0]=(bf16)v.x; o[1]=(bf16)v.y; o[2]=(bf16)v.z; o[3]=(bf16)v.w;
        *(bf16x4*)dst = o;
    } else {
        // per-head transpose: WqT[h][c][e] = Wq[h*64+e][c]
        const int id2 = id - 1408;            // 0..31
        const int h = id2 >> 2, ct = id2 & 3;
        {
            const int e  = t >> 2;
            const int c4 = (t & 3) << 4;
            const float* src = Wq + (size_t)(h * 64 + e) * 256 + ct * 64 + c4;
            float4 v0 = ((const float4*)src)[0];
            float4 v1 = ((const float4*)src)[1];
            float4 v2 = ((const float4*)src)[2];
            float4 v3 = ((const float4*)src)[3];
            float* tr = &tile[e][c4];
            tr[0]=v0.x; tr[1]=v0.y; tr[2]=v0.z; tr[3]=v0.w;
            tr[4]=v1.x; tr[5]=v1.y; tr[6]=v1.z; tr[7]=v1.w;
            tr[8]=v2.x; tr[9]=v2.y; tr[10]=v2.z; tr[11]=v2.w;
            tr[12]=v3.x; tr[13]=v3.y; tr[14]=v3.z; tr[15]=v3.w;
        }
        __syncthreads();
        {
            const int c  = t >> 2;
            const int e4 = (t & 3) << 4;
            bf16x8 o0, o1;
            #pragma unroll
            for (int ii = 0; ii < 8; ++ii) {
                o0[ii] = (bf16)tile[e4 + ii][c];
                o1[ii] = (bf16)tile[e4 + 8 + ii][c];
            }
            bf16* dst = WqT + (size_t)h * 16384 + (size_t)(ct * 64 + c) * 64 + e4;
            *(bf16x8*)dst = o0;
            *(bf16x8*)(dst + 8) = o1;
        }
    }
}

// ------- 128x128-tile MFMA GEMM, B^T form: C[z] = A[z] * Bt[z]^T -------------
// Deep software pipeline: NB=5 LDS ring, 4 K-tiles in flight, counted vmcnt,
// raw s_barrier (no vmcnt(0) drain in the main loop). Designed for the
// 1-block/CU latency-bound regime (grids here are 64..256 blocks).
template<int KDIM, typename OutT>
__global__ __launch_bounds__(256) void gemm128_bt(
    const bf16* __restrict__ A, const bf16* __restrict__ Bt, OutT* __restrict__ C,
    long long sA, long long sBt, long long sC, int ldC)
{
    constexpr int NT = KDIM / 32;      // K-tiles (>= 8 for all instantiations)
    constexpr int NB = 5;              // LDS ring depth
    __shared__ bf16 As[NB][128 * 32];  // 40 KB
    __shared__ bf16 Bs[NB][128 * 32];  // 40 KB
    const int z = blockIdx.z;
    A  += (size_t)z * sA;
    Bt += (size_t)z * sBt;
    C  += (size_t)z * sC;
    const int m0 = blockIdx.x * 128;
    const int n0 = blockIdx.y * 128;
    const int t = threadIdx.x, w = t >> 6, l = t & 63;
    const int srow = w * 16 + (l >> 2);
    const int ske  = (l & 3) * 8;
    const bf16* ga = A  + (size_t)(m0 + srow) * KDIM + ske;
    const bf16* gb = Bt + (size_t)(n0 + srow) * KDIM + ske;
    const int loff = srow * 32 + ske;  // == w*512 + l*8 elems -> lane*16B: gld_lds-safe
    const int lm = l & 15, lq = l >> 4;
    const int wm = (w & 1) * 64, wn = (w >> 1) * 64;

    // prologue: stage tiles 0..NB-2 (4 tiles, 16 loads/thread in flight)
    #pragma unroll
    for (int i = 0; i < NB - 1; ++i) {
        const int k0 = i * 32;
        gld_lds16(ga + k0, &As[i][0] + loff);
        gld_lds16(ga + k0 + (size_t)64 * KDIM, &As[i][0] + 64 * 32 + loff);
        gld_lds16(gb + k0, &Bs[i][0] + loff);
        gld_lds16(gb + k0 + (size_t)64 * KDIM, &Bs[i][0] + 64 * 32 + loff);
    }

    f32x4 acc[4][4] = {};
    int cur = 0, stg = NB - 1;
    for (int kt = 0; kt < NT; ++kt) {
        // Wait (own loads) so tile `kt` is resident, keeping up to 3 newer
        // tiles in flight; then barrier publishes every wave's loads.
        const int remain = NT - 1 - kt;
        if (remain >= 3)      asm volatile("s_waitcnt vmcnt(12)" ::: "memory");
        else if (remain == 2) asm volatile("s_waitcnt vmcnt(8)"  ::: "memory");
        else if (remain == 1) asm volatile("s_waitcnt vmcnt(4)"  ::: "memory");
        else                  asm volatile("s_waitcnt vmcnt(0)"  ::: "memory");
        __builtin_amdgcn_s_barrier();
        __builtin_amdgcn_sched_barrier(0);
        // Stage tile kt+NB-1 into the buffer read LAST iteration (the barrier
        // above guarantees all waves finished reading it).
        const int kst = kt + NB - 1;
        if (kst < NT) {
            const int k0 = kst * 32;
            bf16* la = &As[stg][0] + loff;
            bf16* lb = &Bs[stg][0] + loff;
            gld_lds16(ga + k0, la);
            gld_lds16(ga + k0 + (size_t)64 * KDIM, la + 64 * 32);
            gld_lds16(gb + k0, lb);
            gld_lds16(gb + k0 + (size_t)64 * KDIM, lb + 64 * 32);
        }
        const bf16* Ab = &As[cur][0];
        const bf16* Bb = &Bs[cur][0];
        bf16x8 af[4], bfr[4];
        #pragma unroll
        for (int i = 0; i < 4; ++i)
            af[i] = *(const bf16x8*)(Ab + (wm + i * 16 + lm) * 32 + lq * 8);
        #pragma unroll
        for (int j = 0; j < 4; ++j)
            bfr[j] = *(const bf16x8*)(Bb + (wn + j * 16 + lm) * 32 + lq * 8);
        #pragma unroll
        for (int i = 0; i < 4; ++i)
            #pragma unroll
            for (int j = 0; j < 4; ++j)
                acc[i][j] = __builtin_amdgcn_mfma_f32_16x16x32_bf16(af[i], bfr[j], acc[i][j], 0, 0, 0);
        cur = (cur + 1 == NB) ? 0 : cur + 1;
        stg = (stg + 1 == NB) ? 0 : stg + 1;
    }
    #pragma unroll
    for (int i = 0; i < 4; ++i)
        #pragma unroll
        for (int j = 0; j < 4; ++j) {
            const int row = m0 + wm + i * 16 + lq * 4;
            const int col = n0 + wn + j * 16 + lm;
            OutT* cp = C + (size_t)row * ldC + col;
            #pragma unroll
            for (int r = 0; r < 4; ++r)
                cp[(size_t)r * ldC] = (OutT)acc[i][j][r];
        }
}

// ---- per-(b,h): T_h = (1/64) S_h Wk_h^T  then  WmT_h = WqT_h (x) T_h --------
// S_h [64,256] (k=c'), Wk_h [64,256] (k=c'), WqT_h [256,64] (k=e), T_h [64,64].
// Output WmT[b][c][h*64+d].
// All staging issued up-front (chunk0, Qb, chunk1); counted vmcnt(16) lets
// Qb+chunk1 loads stay in flight under chunk0's MFMAs.
__global__ __launch_bounds__(256) void tm_kernel(
    const bf16* __restrict__ S, const bf16* __restrict__ WkB,
    const bf16* __restrict__ WqT, bf16* __restrict__ WmT)
{
    __shared__ __align__(16) bf16 Sc[2][8192];   // 32KB: S chunks [64][128]
    __shared__ __align__(16) bf16 Kc[2][8192];   // 32KB: K chunks [64][128]
    __shared__ __align__(16) bf16 Qb[16384];     // 32KB: WqT_h
    __shared__ __align__(16) bf16 Tb[4096];      //  8KB: T_h [64][64]

    const int bh = blockIdx.x;
    const int b = bh >> 3, h = bh & 7;
    const bf16* Sg = S   + (size_t)b * 131072 + (size_t)h * 64 * 256;
    const bf16* Kg = WkB + (size_t)h * 64 * 256;
    const bf16* Qg = WqT + (size_t)h * 16384;
    const int t = threadIdx.x, w = t >> 6, l = t & 63;
    const int lm = l & 15, lq = l >> 4;

    // stage chunk0 (oldest: 8 instr), then Qb (8), then chunk1 (8)
    #pragma unroll
    for (int it = 0; it < 4; ++it) {
        const int idx = it * 256 + t;
        const int r = idx >> 4, s2 = idx & 15;
        const int gs = (s2 ^ (r & 7)) * 8;
        gld_lds16(Sg + (size_t)r * 256 + gs, &Sc[0][0] + r * 128 + s2 * 8);
        gld_lds16(Kg + (size_t)r * 256 + gs, &Kc[0][0] + r * 128 + s2 * 8);
    }
    #pragma unroll
    for (int it = 0; it < 8; ++it) {
        const int idx = it * 256 + t;
        const int r = idx >> 3, s2 = idx & 7;
        gld_lds16(Qg + (size_t)r * 64 + (s2 ^ (r & 7)) * 8, Qb + r * 64 + s2 * 8);
    }
    #pragma unroll
    for (int it = 0; it < 4; ++it) {
        const int idx = it * 256 + t;
        const int r = idx >> 4, s2 = idx & 15;
        const int gs = (s2 ^ (r & 7)) * 8;
        gld_lds16(Sg + (size_t)r * 256 + 128 + gs, &Sc[1][0] + r * 128 + s2 * 8);
        gld_lds16(Kg + (size_t)r * 256 + 128 + gs, &Kc[1][0] + r * 128 + s2 * 8);
    }

    f32x4 accT[4] = {};
    // chunk0 resident (oldest 8 retired); Qb + chunk1 (16) stay in flight
    asm volatile("s_waitcnt vmcnt(16)" ::: "memory");
    __builtin_amdgcn_s_barrier();
    __builtin_amdgcn_sched_barrier(0);
    #pragma unroll
    for (int ks = 0; ks < 4; ++ks) {
        const int q = ks * 4 + lq;                 // 0..15
        const int ra = w * 16 + lm;
        bf16x8 a = *(const bf16x8*)(&Sc[0][0] + ra * 128 + (q ^ (ra & 7)) * 8);
        #pragma unroll
        for (int nf = 0; nf < 4; ++nf) {
            const int rb = nf * 16 + lm;
            bf16x8 bb = *(const bf16x8*)(&Kc[0][0] + rb * 128 + (q ^ (rb & 7)) * 8);
            accT[nf] = __builtin_amdgcn_mfma_f32_16x16x32_bf16(a, bb, accT[nf], 0, 0, 0);
        }
    }
    asm volatile("s_waitcnt vmcnt(0)" ::: "memory");
    __builtin_amdgcn_s_barrier();
    __builtin_amdgcn_sched_barrier(0);
    #pragma unroll
    for (int ks = 0; ks < 4; ++ks) {
        const int q = ks * 4 + lq;
        const int ra = w * 16 + lm;
        bf16x8 a = *(const bf16x8*)(&Sc[1][0] + ra * 128 + (q ^ (ra & 7)) * 8);
        #pragma unroll
        for (int nf = 0; nf < 4; ++nf) {
            const int rb = nf * 16 + lm;
            bf16x8 bb = *(const bf16x8*)(&Kc[1][0] + rb * 128 + (q ^ (rb & 7)) * 8);
            accT[nf] = __builtin_amdgcn_mfma_f32_16x16x32_bf16(a, bb, accT[nf], 0, 0, 0);
        }
    }
    // write T (scaled) into Tb, swizzled [64][64]
    #pragma unroll
    for (int nf = 0; nf < 4; ++nf)
        #pragma unroll
        for (int ri = 0; ri < 4; ++ri) {
            const int row = w * 16 + lq * 4 + ri;
            const int col = nf * 16 + lm;
            Tb[row * 64 + (((col >> 3) ^ (row & 7)) << 3) + (col & 7)] =
                (bf16)(accT[nf][ri] * 0.015625f);
        }
    __syncthreads();

    // phase M: WmT_h[c,d] = sum_e WqT_h[c,e] T_h[d,e], M=256 N=64 K=64
    f32x4 accM[4][4] = {};
    #pragma unroll
    for (int ks = 0; ks < 2; ++ks) {
        const int q = ks * 4 + lq;                     // 0..7
        bf16x8 bfrag[4];
        #pragma unroll
        for (int nf = 0; nf < 4; ++nf) {
            const int rb = nf * 16 + lm;
            bfrag[nf] = *(const bf16x8*)(Tb + rb * 64 + (q ^ (rb & 7)) * 8);
        }
        #pragma unroll
        for (int mf = 0; mf < 4; ++mf) {
            const int ra = w * 64 + mf * 16 + lm;
            bf16x8 a = *(const bf16x8*)(Qb + ra * 64 + (q ^ (ra & 7)) * 8);
            #pragma unroll
            for (int nf = 0; nf < 4; ++nf)
                accM[mf][nf] = __builtin_amdgcn_mfma_f32_16x16x32_bf16(a, bfrag[nf], accM[mf][nf], 0, 0, 0);
        }
    }
    bf16* Wg = WmT + (size_t)b * 131072 + h * 64;
    #pragma unroll
    for (int mf = 0; mf < 4; ++mf)
        #pragma unroll
        for (int nf = 0; nf < 4; ++nf)
            #pragma unroll
            for (int ri = 0; ri < 4; ++ri) {
                const int c = w * 64 + mf * 16 + lq * 4 + ri;
                const int d = nf * 16 + lm;
                Wg[(size_t)c * 512 + d] = (bf16)accM[mf][nf][ri];
            }
}

// ------------- InstanceNorm over L + gamma residual + LeakyReLU --------------
__global__ __launch_bounds__(256) void norm_kernel(
    const bf16* __restrict__ o, const bf16* __restrict__ xB,
    const float* __restrict__ gamma, float* __restrict__ y)
{
    const size_t row = blockIdx.x;
    const bf16* orow = o + row * 1024;
    const bf16* xrow = xB + row * 1024;
    float* yrow = y + row * 1024;
    const int tid = threadIdx.x;

    bf16x4 ov = *(const bf16x4*)(orow + tid * 4);
    float4 v = {(float)ov[0], (float)ov[1], (float)ov[2], (float)ov[3]};
    float s  = v.x + v.y + v.z + v.w;
    float ss = v.x * v.x + v.y * v.y + v.z * v.z + v.w * v.w;
    #pragma unroll
    for (int off = 32; off > 0; off >>= 1) {
        s  += __shfl_down(s, off);
        ss += __shfl_down(ss, off);
    }
    __shared__ float red[10];
    const int wave = tid >> 6, lane = tid & 63;
    if (lane == 0) { red[wave] = s; red[4 + wave] = ss; }
    __syncthreads();
    if (tid == 0) {
        float a  = red[0] + red[1] + red[2] + red[3];
        float b2 = red[4] + red[5] + red[6] + red[7];
        float mu = a * (1.0f / 1024.0f);
        float var = b2 * (1.0f / 1024.0f) - mu * mu;
        red[8] = mu;
        red[9] = rsqrtf(var + EPS);
    }
    __syncthreads();
    const float mu = red[8], inv = red[9], g = gamma[0];
    bf16x4 xv4 = *(const bf16x4*)(xrow + tid * 4);
    float4 r;
    r.x = (v.x - mu) * inv * g + (float)xv4[0];
    r.y = (v.y - mu) * inv * g + (float)xv4[1];
    r.z = (v.z - mu) * inv * g + (float)xv4[2];
    r.w = (v.w - mu) * inv * g + (float)xv4[3];
    r.x = r.x >= 0.f ? r.x : SLOPE * r.x;
    r.y = r.y >= 0.f ? r.y : SLOPE * r.y;
    r.z = r.z >= 0.f ? r.z : SLOPE * r.z;
    r.w = r.w >= 0.f ? r.w : SLOPE * r.w;
    ((float4*)yrow)[tid] = r;
}

extern "C" void kernel_launch(void* const* d_in, const int* in_sizes, int n_in,
                              void* d_out, int out_size, void* d_ws, size_t ws_size,
                              hipStream_t stream) {
    const float* x     = (const float*)d_in[0];
    const float* Wq    = (const float*)d_in[1];
    const float* Wk    = (const float*)d_in[2];
    const float* Wv    = (const float*)d_in[3];
    const float* Wo    = (const float*)d_in[4];
    const float* gamma = (const float*)d_in[5];
    float* y = (float*)d_out;

    char* wsb = (char*)d_ws;
    bf16* xT  = (bf16*)(wsb);                   //  8,388,608
    bf16* xB  = (bf16*)(wsb +  8388608);        //  8,388,608
    bf16* WkB = (bf16*)(wsb + 16777216);        //    262,144
    bf16* WvB = (bf16*)(wsb + 17039360);        //    262,144
    bf16* WoB = (bf16*)(wsb + 17301504);        //    262,144
    bf16* WqT = (bf16*)(wsb + 17563648);        //    262,144
    bf16* G   = (bf16*)(wsb + 17825792);        //  2,097,152
    bf16* S   = (bf16*)(wsb + 19922944);        //  4,194,304
    bf16* WmT = (bf16*)(wsb + 24117248);        //  4,194,304
    bf16* Wt  = (bf16*)(wsb + 28311552);        //  2,097,152
    bf16* o   = (bf16*)(wsb + 30408704);        //  8,388,608  (end 38,797,312)

    prep_kernel<<<dim3(1440), 256, 0, stream>>>(x, Wq, Wk, Wv, Wo, xT, xB, WkB, WvB, WoB, WqT);

    // G[b] = xB[b] (x) xB[b]  : [256,256], K=1024 (symmetric Gram)
    gemm128_bt<1024, bf16><<<dim3(2, 2, 16), 256, 0, stream>>>(
        xB, xB, G, 262144LL, 262144LL, 65536LL, 256);

    // S[b] = WvB (x) G[b] : [512,256], K=256
    gemm128_bt<256, bf16><<<dim3(4, 2, 16), 256, 0, stream>>>(
        WvB, G, S, 0LL, 65536LL, 131072LL, 256);

    // T_h = (1/64) S_h Wk_h^T ; WmT[b][c][hd] = sum_e Wq_h[e,c] T_h[d,e]
    tm_kernel<<<dim3(128), 256, 0, stream>>>(S, WkB, WqT, WmT);

    // Wt[b] = WoB (x) WmT[b] : [256,256], K=512
    gemm128_bt<512, bf16><<<dim3(2, 2, 16), 256, 0, stream>>>(
        WoB, WmT, Wt, 0LL, 131072LL, 65536LL, 256);

    // o[b] = Wt[b] (x) xT[b] : [256,1024], K=256
    gemm128_bt<256, bf16><<<dim3(2, 8, 16), 256, 0, stream>>>(
        Wt, xT, o, 65536LL, 262144LL, 262144LL, 1024);

    norm_kernel<<<dim3(4096), 256, 0, stream>>>(o, xB, gamma, y);
}

// Round 2
// 123.827 us; speedup vs baseline: 1.1237x; 1.1237x over previous
//
#include <hip/hip_runtime.h>

typedef __bf16 bf16;
typedef bf16 bf16x8 __attribute__((ext_vector_type(8)));
typedef bf16 bf16x4 __attribute__((ext_vector_type(4)));
typedef float f32x4 __attribute__((ext_vector_type(4)));

#define EPS 1e-5f
#define SLOPE 0.01f

// async global->LDS, 16B/lane. Invariant: lds ptr == wave-uniform base + lane*16B.
__device__ __forceinline__ void gld_lds16(const bf16* g, bf16* l) {
    __builtin_amdgcn_global_load_lds(
        (const __attribute__((address_space(1))) unsigned int*)g,
        (__attribute__((address_space(3))) unsigned int*)l, 16, 0, 0);
}

// ---------- prep: xT[b][l][c], xB[b][c][l], Wk/Wv/Wo bf16, WqT[h][c][e] ------
__global__ __launch_bounds__(256) void prep_kernel(
    const float* __restrict__ x,
    const float* __restrict__ Wq, const float* __restrict__ Wk,
    const float* __restrict__ Wv, const float* __restrict__ Wo,
    bf16* __restrict__ xT, bf16* __restrict__ xB,
    bf16* __restrict__ WkB, bf16* __restrict__ WvB,
    bf16* __restrict__ WoB, bf16* __restrict__ WqT)
{
    __shared__ float tile[64][65];
    const int id = blockIdx.x;
    const int t = threadIdx.x;
    if (id < 1024) {
        const int lt = id & 15, ct = (id >> 4) & 3, b = id >> 6;
        {
            const int cl = t >> 2;            // c within tile
            const int l4 = (t & 3) << 4;      // l within tile (16-chunks)
            const float* src = x + (size_t)(b * 256 + ct * 64 + cl) * 1024 + lt * 64 + l4;
            float4 v0 = ((const float4*)src)[0];
            float4 v1 = ((const float4*)src)[1];
            float4 v2 = ((const float4*)src)[2];
            float4 v3 = ((const float4*)src)[3];
            bf16x8 r0, r1;
            r0[0]=(bf16)v0.x; r0[1]=(bf16)v0.y; r0[2]=(bf16)v0.z; r0[3]=(bf16)v0.w;
            r0[4]=(bf16)v1.x; r0[5]=(bf16)v1.y; r0[6]=(bf16)v1.z; r0[7]=(bf16)v1.w;
            r1[0]=(bf16)v2.x; r1[1]=(bf16)v2.y; r1[2]=(bf16)v2.z; r1[3]=(bf16)v2.w;
            r1[4]=(bf16)v3.x; r1[5]=(bf16)v3.y; r1[6]=(bf16)v3.z; r1[7]=(bf16)v3.w;
            bf16* xbd = xB + (size_t)(b * 256 + ct * 64 + cl) * 1024 + lt * 64 + l4;
            *(bf16x8*)xbd = r0;
            *(bf16x8*)(xbd + 8) = r1;
            float* tr = &tile[cl][l4];
            tr[0]=v0.x; tr[1]=v0.y; tr[2]=v0.z; tr[3]=v0.w;
            tr[4]=v1.x; tr[5]=v1.y; tr[6]=v1.z; tr[7]=v1.w;
            tr[8]=v2.x; tr[9]=v2.y; tr[10]=v2.z; tr[11]=v2.w;
            tr[12]=v3.x; tr[13]=v3.y; tr[14]=v3.z; tr[15]=v3.w;
        }
        __syncthreads();
        {
            const int lw = t >> 2;            // l within tile
            const int ec = (t & 3) << 4;      // c within tile
            bf16x8 o0, o1;
            #pragma unroll
            for (int ii = 0; ii < 8; ++ii) {
                o0[ii] = (bf16)tile[ec + ii][lw];
                o1[ii] = (bf16)tile[ec + 8 + ii][lw];
            }
            bf16* dst = xT + (size_t)(b * 1024 + lt * 64 + lw) * 256 + ct * 64 + ec;
            *(bf16x8*)dst = o0;
            *(bf16x8*)(dst + 8) = o1;
        }
    } else if (id < 1408) {
        // straight bf16 casts of Wk, Wv, Wo
        const int i = (id - 1024) * 1024 + t * 4;    // [0, 393216)
        const float* src; bf16* dst;
        if (i < 131072)      { src = Wk + i;            dst = WkB + i; }
        else if (i < 262144) { src = Wv + (i - 131072); dst = WvB + (i - 131072); }
        else                 { src = Wo + (i - 262144); dst = WoB + (i - 262144); }
        float4 v = *(const float4*)src;
        bf16x4 o;
        o[0]=(bf16)v.x; o[1]=(bf16)v.y; o[2]=(bf16)v.z; o[3]=(bf16)v.w;
        *(bf16x4*)dst = o;
    } else {
        // per-head transpose: WqT[h][c][e] = Wq[h*64+e][c]
        const int id2 = id - 1408;            // 0..31
        const int h = id2 >> 2, ct = id2 & 3;
        {
            const int e  = t >> 2;
            const int c4 = (t & 3) << 4;
            const float* src = Wq + (size_t)(h * 64 + e) * 256 + ct * 64 + c4;
            float4 v0 = ((const float4*)src)[0];
            float4 v1 = ((const float4*)src)[1];
            float4 v2 = ((const float4*)src)[2];
            float4 v3 = ((const float4*)src)[3];
            float* tr = &tile[e][c4];
            tr[0]=v0.x; tr[1]=v0.y; tr[2]=v0.z; tr[3]=v0.w;
            tr[4]=v1.x; tr[5]=v1.y; tr[6]=v1.z; tr[7]=v1.w;
            tr[8]=v2.x; tr[9]=v2.y; tr[10]=v2.z; tr[11]=v2.w;
            tr[12]=v3.x; tr[13]=v3.y; tr[14]=v3.z; tr[15]=v3.w;
        }
        __syncthreads();
        {
            const int c  = t >> 2;
            const int e4 = (t & 3) << 4;
            bf16x8 o0, o1;
            #pragma unroll
            for (int ii = 0; ii < 8; ++ii) {
                o0[ii] = (bf16)tile[e4 + ii][c];
                o1[ii] = (bf16)tile[e4 + 8 + ii][c];
            }
            bf16* dst = WqT + (size_t)h * 16384 + (size_t)(ct * 64 + c) * 64 + e4;
            *(bf16x8*)dst = o0;
            *(bf16x8*)(dst + 8) = o1;
        }
    }
}

// ------- 128x128-tile MFMA GEMM, B^T form: C[z] = A[z] * Bt[z]^T -------------
// NB=5 LDS ring, FULLY UNROLLED so every ring index is a compile-time constant
// (lets the waitcnt pass prove stage-buffer/read-buffer disjointness and keep
// the counted-vmcnt pipeline instead of inserting vmcnt(0) drains).
template<int KDIM, typename OutT>
__global__ __launch_bounds__(256) void gemm128_bt(
    const bf16* __restrict__ A, const bf16* __restrict__ Bt, OutT* __restrict__ C,
    long long sA, long long sBt, long long sC, int ldC)
{
    constexpr int NT = KDIM / 32;      // K-tiles
    constexpr int NB = 5;              // LDS ring depth (4 tiles in flight)
    __shared__ bf16 As[NB][128 * 32];  // 40 KB
    __shared__ bf16 Bs[NB][128 * 32];  // 40 KB
    const int z = blockIdx.z;
    A  += (size_t)z * sA;
    Bt += (size_t)z * sBt;
    C  += (size_t)z * sC;
    const int m0 = blockIdx.x * 128;
    const int n0 = blockIdx.y * 128;
    const int t = threadIdx.x, w = t >> 6, l = t & 63;
    const int srow = w * 16 + (l >> 2);
    const int ske  = (l & 3) * 8;
    const bf16* ga = A  + (size_t)(m0 + srow) * KDIM + ske;
    const bf16* gb = Bt + (size_t)(n0 + srow) * KDIM + ske;
    const int loff = srow * 32 + ske;  // lane*16B within wave: gld_lds-safe
    const int lm = l & 15, lq = l >> 4;
    const int wm = (w & 1) * 64, wn = (w >> 1) * 64;

    // prologue: stage tiles 0..NB-2 (16 loads/thread in flight)
    #pragma unroll
    for (int i = 0; i < NB - 1; ++i) {
        const int k0 = i * 32;
        gld_lds16(ga + k0, &As[i][0] + loff);
        gld_lds16(ga + k0 + (size_t)64 * KDIM, &As[i][0] + 64 * 32 + loff);
        gld_lds16(gb + k0, &Bs[i][0] + loff);
        gld_lds16(gb + k0 + (size_t)64 * KDIM, &Bs[i][0] + 64 * 32 + loff);
    }

    f32x4 acc[4][4] = {};
    #pragma unroll
    for (int kt = 0; kt < NT; ++kt) {
        const int cur = kt % NB;
        const int stg = (kt + NB - 1) % NB;
        const int remain = NT - 1 - kt;
        // own tile kt resident; up to 3 newer tiles stay in flight
        if (remain >= 3)      asm volatile("s_waitcnt vmcnt(12)" ::: "memory");
        else if (remain == 2) asm volatile("s_waitcnt vmcnt(8)"  ::: "memory");
        else if (remain == 1) asm volatile("s_waitcnt vmcnt(4)"  ::: "memory");
        else                  asm volatile("s_waitcnt vmcnt(0)"  ::: "memory");
        __builtin_amdgcn_s_barrier();          // publish tile kt; retire reads of buf stg
        __builtin_amdgcn_sched_barrier(0);
        if (kt + NB - 1 < NT) {                // stage tile kt+4 into buf read last iter
            const int k0 = (kt + NB - 1) * 32;
            gld_lds16(ga + k0, &As[stg][0] + loff);
            gld_lds16(ga + k0 + (size_t)64 * KDIM, &As[stg][0] + 64 * 32 + loff);
            gld_lds16(gb + k0, &Bs[stg][0] + loff);
            gld_lds16(gb + k0 + (size_t)64 * KDIM, &Bs[stg][0] + 64 * 32 + loff);
        }
        bf16x8 af[4], bfr[4];
        #pragma unroll
        for (int i = 0; i < 4; ++i)
            af[i] = *(const bf16x8*)(&As[cur][0] + (wm + i * 16 + lm) * 32 + lq * 8);
        #pragma unroll
        for (int j = 0; j < 4; ++j)
            bfr[j] = *(const bf16x8*)(&Bs[cur][0] + (wn + j * 16 + lm) * 32 + lq * 8);
        #pragma unroll
        for (int i = 0; i < 4; ++i)
            #pragma unroll
            for (int j = 0; j < 4; ++j)
                acc[i][j] = __builtin_amdgcn_mfma_f32_16x16x32_bf16(af[i], bfr[j], acc[i][j], 0, 0, 0);
    }
    #pragma unroll
    for (int i = 0; i < 4; ++i)
        #pragma unroll
        for (int j = 0; j < 4; ++j) {
            const int row = m0 + wm + i * 16 + lq * 4;
            const int col = n0 + wn + j * 16 + lm;
            OutT* cp = C + (size_t)row * ldC + col;
            #pragma unroll
            for (int r = 0; r < 4; ++r)
                cp[(size_t)r * ldC] = (OutT)acc[i][j][r];
        }
}

// ------- 64x64-tile MFMA GEMM, B^T form, for the grid-starved stages ---------
// 256 threads: wave w owns rows w*16..w*16+15 of the 64-row tile, all 64 cols.
// Same NB=5 compile-time ring + counted vmcnt. 2 gld/iter -> waits 6/4/2/0.
template<int KDIM, typename OutT>
__global__ __launch_bounds__(256) void gemm64_bt(
    const bf16* __restrict__ A, const bf16* __restrict__ Bt, OutT* __restrict__ C,
    long long sA, long long sBt, long long sC, int ldC)
{
    constexpr int NT = KDIM / 32;
    constexpr int NB = 5;
    __shared__ bf16 As[NB][64 * 32];   // 20 KB
    __shared__ bf16 Bs[NB][64 * 32];   // 20 KB
    const int z = blockIdx.z;
    A  += (size_t)z * sA;
    Bt += (size_t)z * sBt;
    C  += (size_t)z * sC;
    const int m0 = blockIdx.x * 64;
    const int n0 = blockIdx.y * 64;
    const int t = threadIdx.x, w = t >> 6, l = t & 63;
    const int srow = t >> 2;           // 0..63
    const int ske  = (t & 3) * 8;
    const bf16* ga = A  + (size_t)(m0 + srow) * KDIM + ske;
    const bf16* gb = Bt + (size_t)(n0 + srow) * KDIM + ske;
    const int loff = srow * 32 + ske;  // == t*8 elems == lane*16B within wave
    const int lm = l & 15, lq = l >> 4;

    #pragma unroll
    for (int i = 0; i < NB - 1; ++i) {
        const int k0 = i * 32;
        gld_lds16(ga + k0, &As[i][0] + loff);
        gld_lds16(gb + k0, &Bs[i][0] + loff);
    }

    f32x4 acc[4] = {};
    #pragma unroll
    for (int kt = 0; kt < NT; ++kt) {
        const int cur = kt % NB;
        const int stg = (kt + NB - 1) % NB;
        const int remain = NT - 1 - kt;
        if (remain >= 3)      asm volatile("s_waitcnt vmcnt(6)" ::: "memory");
        else if (remain == 2) asm volatile("s_waitcnt vmcnt(4)" ::: "memory");
        else if (remain == 1) asm volatile("s_waitcnt vmcnt(2)" ::: "memory");
        else                  asm volatile("s_waitcnt vmcnt(0)" ::: "memory");
        __builtin_amdgcn_s_barrier();
        __builtin_amdgcn_sched_barrier(0);
        if (kt + NB - 1 < NT) {
            const int k0 = (kt + NB - 1) * 32;
            gld_lds16(ga + k0, &As[stg][0] + loff);
            gld_lds16(gb + k0, &Bs[stg][0] + loff);
        }
        bf16x8 af = *(const bf16x8*)(&As[cur][0] + (w * 16 + lm) * 32 + lq * 8);
        bf16x8 bfr[4];
        #pragma unroll
        for (int j = 0; j < 4; ++j)
            bfr[j] = *(const bf16x8*)(&Bs[cur][0] + (j * 16 + lm) * 32 + lq * 8);
        #pragma unroll
        for (int j = 0; j < 4; ++j)
            acc[j] = __builtin_amdgcn_mfma_f32_16x16x32_bf16(af, bfr[j], acc[j], 0, 0, 0);
    }
    #pragma unroll
    for (int j = 0; j < 4; ++j) {
        const int row = m0 + w * 16 + lq * 4;
        const int col = n0 + j * 16 + lm;
        OutT* cp = C + (size_t)row * ldC + col;
        #pragma unroll
        for (int r = 0; r < 4; ++r)
            cp[(size_t)r * ldC] = (OutT)acc[j][r];
    }
}

// ---- per-(b,h): T_h = (1/64) S_h Wk_h^T  then  WmT_h = WqT_h (x) T_h --------
__global__ __launch_bounds__(256) void tm_kernel(
    const bf16* __restrict__ S, const bf16* __restrict__ WkB,
    const bf16* __restrict__ WqT, bf16* __restrict__ WmT)
{
    __shared__ __align__(16) bf16 Sc[2][8192];   // 32KB: S chunks [64][128]
    __shared__ __align__(16) bf16 Kc[2][8192];   // 32KB: K chunks [64][128]
    __shared__ __align__(16) bf16 Qb[16384];     // 32KB: WqT_h
    __shared__ __align__(16) bf16 Tb[4096];      //  8KB: T_h [64][64]

    const int bh = blockIdx.x;
    const int b = bh >> 3, h = bh & 7;
    const bf16* Sg = S   + (size_t)b * 131072 + (size_t)h * 64 * 256;
    const bf16* Kg = WkB + (size_t)h * 64 * 256;
    const bf16* Qg = WqT + (size_t)h * 16384;
    const int t = threadIdx.x, w = t >> 6, l = t & 63;
    const int lm = l & 15, lq = l >> 4;

    // stage chunk0 (oldest: 8 instr), then Qb (8), then chunk1 (8)
    #pragma unroll
    for (int it = 0; it < 4; ++it) {
        const int idx = it * 256 + t;
        const int r = idx >> 4, s2 = idx & 15;
        const int gs = (s2 ^ (r & 7)) * 8;
        gld_lds16(Sg + (size_t)r * 256 + gs, &Sc[0][0] + r * 128 + s2 * 8);
        gld_lds16(Kg + (size_t)r * 256 + gs, &Kc[0][0] + r * 128 + s2 * 8);
    }
    #pragma unroll
    for (int it = 0; it < 8; ++it) {
        const int idx = it * 256 + t;
        const int r = idx >> 3, s2 = idx & 7;
        gld_lds16(Qg + (size_t)r * 64 + (s2 ^ (r & 7)) * 8, Qb + r * 64 + s2 * 8);
    }
    #pragma unroll
    for (int it = 0; it < 4; ++it) {
        const int idx = it * 256 + t;
        const int r = idx >> 4, s2 = idx & 15;
        const int gs = (s2 ^ (r & 7)) * 8;
        gld_lds16(Sg + (size_t)r * 256 + 128 + gs, &Sc[1][0] + r * 128 + s2 * 8);
        gld_lds16(Kg + (size_t)r * 256 + 128 + gs, &Kc[1][0] + r * 128 + s2 * 8);
    }

    f32x4 accT[4] = {};
    // chunk0 resident (oldest 8 retired); Qb + chunk1 (16) stay in flight
    asm volatile("s_waitcnt vmcnt(16)" ::: "memory");
    __builtin_amdgcn_s_barrier();
    __builtin_amdgcn_sched_barrier(0);
    #pragma unroll
    for (int ks = 0; ks < 4; ++ks) {
        const int q = ks * 4 + lq;                 // 0..15
        const int ra = w * 16 + lm;
        bf16x8 a = *(const bf16x8*)(&Sc[0][0] + ra * 128 + (q ^ (ra & 7)) * 8);
        #pragma unroll
        for (int nf = 0; nf < 4; ++nf) {
            const int rb = nf * 16 + lm;
            bf16x8 bb = *(const bf16x8*)(&Kc[0][0] + rb * 128 + (q ^ (rb & 7)) * 8);
            accT[nf] = __builtin_amdgcn_mfma_f32_16x16x32_bf16(a, bb, accT[nf], 0, 0, 0);
        }
    }
    asm volatile("s_waitcnt vmcnt(0)" ::: "memory");
    __builtin_amdgcn_s_barrier();
    __builtin_amdgcn_sched_barrier(0);
    #pragma unroll
    for (int ks = 0; ks < 4; ++ks) {
        const int q = ks * 4 + lq;
        const int ra = w * 16 + lm;
        bf16x8 a = *(const bf16x8*)(&Sc[1][0] + ra * 128 + (q ^ (ra & 7)) * 8);
        #pragma unroll
        for (int nf = 0; nf < 4; ++nf) {
            const int rb = nf * 16 + lm;
            bf16x8 bb = *(const bf16x8*)(&Kc[1][0] + rb * 128 + (q ^ (rb & 7)) * 8);
            accT[nf] = __builtin_amdgcn_mfma_f32_16x16x32_bf16(a, bb, accT[nf], 0, 0, 0);
        }
    }
    // write T (scaled) into Tb, swizzled [64][64]
    #pragma unroll
    for (int nf = 0; nf < 4; ++nf)
        #pragma unroll
        for (int ri = 0; ri < 4; ++ri) {
            const int row = w * 16 + lq * 4 + ri;
            const int col = nf * 16 + lm;
            Tb[row * 64 + (((col >> 3) ^ (row & 7)) << 3) + (col & 7)] =
                (bf16)(accT[nf][ri] * 0.015625f);
        }
    __syncthreads();

    // phase M: WmT_h[c,d] = sum_e WqT_h[c,e] T_h[d,e], M=256 N=64 K=64
    f32x4 accM[4][4] = {};
    #pragma unroll
    for (int ks = 0; ks < 2; ++ks) {
        const int q = ks * 4 + lq;                     // 0..7
        bf16x8 bfrag[4];
        #pragma unroll
        for (int nf = 0; nf < 4; ++nf) {
            const int rb = nf * 16 + lm;
            bfrag[nf] = *(const bf16x8*)(Tb + rb * 64 + (q ^ (rb & 7)) * 8);
        }
        #pragma unroll
        for (int mf = 0; mf < 4; ++mf) {
            const int ra = w * 64 + mf * 16 + lm;
            bf16x8 a = *(const bf16x8*)(Qb + ra * 64 + (q ^ (ra & 7)) * 8);
            #pragma unroll
            for (int nf = 0; nf < 4; ++nf)
                accM[mf][nf] = __builtin_amdgcn_mfma_f32_16x16x32_bf16(a, bfrag[nf], accM[mf][nf], 0, 0, 0);
        }
    }
    bf16* Wg = WmT + (size_t)b * 131072 + h * 64;
    #pragma unroll
    for (int mf = 0; mf < 4; ++mf)
        #pragma unroll
        for (int nf = 0; nf < 4; ++nf)
            #pragma unroll
            for (int ri = 0; ri < 4; ++ri) {
                const int c = w * 64 + mf * 16 + lq * 4 + ri;
                const int d = nf * 16 + lm;
                Wg[(size_t)c * 512 + d] = (bf16)accM[mf][nf][ri];
            }
}

// ------------- InstanceNorm over L + gamma residual + LeakyReLU --------------
__global__ __launch_bounds__(256) void norm_kernel(
    const bf16* __restrict__ o, const bf16* __restrict__ xB,
    const float* __restrict__ gamma, float* __restrict__ y)
{
    const size_t row = blockIdx.x;
    const bf16* orow = o + row * 1024;
    const bf16* xrow = xB + row * 1024;
    float* yrow = y + row * 1024;
    const int tid = threadIdx.x;

    bf16x4 ov = *(const bf16x4*)(orow + tid * 4);
    float4 v = {(float)ov[0], (float)ov[1], (float)ov[2], (float)ov[3]};
    float s  = v.x + v.y + v.z + v.w;
    float ss = v.x * v.x + v.y * v.y + v.z * v.z + v.w * v.w;
    #pragma unroll
    for (int off = 32; off > 0; off >>= 1) {
        s  += __shfl_down(s, off);
        ss += __shfl_down(ss, off);
    }
    __shared__ float red[10];
    const int wave = tid >> 6, lane = tid & 63;
    if (lane == 0) { red[wave] = s; red[4 + wave] = ss; }
    __syncthreads();
    if (tid == 0) {
        float a  = red[0] + red[1] + red[2] + red[3];
        float b2 = red[4] + red[5] + red[6] + red[7];
        float mu = a * (1.0f / 1024.0f);
        float var = b2 * (1.0f / 1024.0f) - mu * mu;
        red[8] = mu;
        red[9] = rsqrtf(var + EPS);
    }
    __syncthreads();
    const float mu = red[8], inv = red[9], g = gamma[0];
    bf16x4 xv4 = *(const bf16x4*)(xrow + tid * 4);
    float4 r;
    r.x = (v.x - mu) * inv * g + (float)xv4[0];
    r.y = (v.y - mu) * inv * g + (float)xv4[1];
    r.z = (v.z - mu) * inv * g + (float)xv4[2];
    r.w = (v.w - mu) * inv * g + (float)xv4[3];
    r.x = r.x >= 0.f ? r.x : SLOPE * r.x;
    r.y = r.y >= 0.f ? r.y : SLOPE * r.y;
    r.z = r.z >= 0.f ? r.z : SLOPE * r.z;
    r.w = r.w >= 0.f ? r.w : SLOPE * r.w;
    ((float4*)yrow)[tid] = r;
}

extern "C" void kernel_launch(void* const* d_in, const int* in_sizes, int n_in,
                              void* d_out, int out_size, void* d_ws, size_t ws_size,
                              hipStream_t stream) {
    const float* x     = (const float*)d_in[0];
    const float* Wq    = (const float*)d_in[1];
    const float* Wk    = (const float*)d_in[2];
    const float* Wv    = (const float*)d_in[3];
    const float* Wo    = (const float*)d_in[4];
    const float* gamma = (const float*)d_in[5];
    float* y = (float*)d_out;

    char* wsb = (char*)d_ws;
    bf16* xT  = (bf16*)(wsb);                   //  8,388,608
    bf16* xB  = (bf16*)(wsb +  8388608);        //  8,388,608
    bf16* WkB = (bf16*)(wsb + 16777216);        //    262,144
    bf16* WvB = (bf16*)(wsb + 17039360);        //    262,144
    bf16* WoB = (bf16*)(wsb + 17301504);        //    262,144
    bf16* WqT = (bf16*)(wsb + 17563648);        //    262,144
    bf16* G   = (bf16*)(wsb + 17825792);        //  2,097,152
    bf16* S   = (bf16*)(wsb + 19922944);        //  4,194,304
    bf16* WmT = (bf16*)(wsb + 24117248);        //  4,194,304
    bf16* Wt  = (bf16*)(wsb + 28311552);        //  2,097,152
    bf16* o   = (bf16*)(wsb + 30408704);        //  8,388,608  (end 38,797,312)

    prep_kernel<<<dim3(1440), 256, 0, stream>>>(x, Wq, Wk, Wv, Wo, xT, xB, WkB, WvB, WoB, WqT);

    // G[b] = xB[b] (x) xB[b] : [256,256], K=1024 -- 64x64 tiles, 256 blocks
    gemm64_bt<1024, bf16><<<dim3(4, 4, 16), 256, 0, stream>>>(
        xB, xB, G, 262144LL, 262144LL, 65536LL, 256);

    // S[b] = WvB (x) G[b] : [512,256], K=256 -- 64x64 tiles, 512 blocks
    gemm64_bt<256, bf16><<<dim3(8, 4, 16), 256, 0, stream>>>(
        WvB, G, S, 0LL, 65536LL, 131072LL, 256);

    // T_h = (1/64) S_h Wk_h^T ; WmT[b][c][hd] = sum_e Wq_h[e,c] T_h[d,e]
    tm_kernel<<<dim3(128), 256, 0, stream>>>(S, WkB, WqT, WmT);

    // Wt[b] = WoB (x) WmT[b] : [256,256], K=512 -- 64x64 tiles, 256 blocks
    gemm64_bt<512, bf16><<<dim3(4, 4, 16), 256, 0, stream>>>(
        WoB, WmT, Wt, 0LL, 131072LL, 65536LL, 256);

    // o[b] = Wt[b] (x) xT[b] : [256,1024], K=256 -- 128x128 tiles, 256 blocks
    gemm128_bt<256, bf16><<<dim3(2, 8, 16), 256, 0, stream>>>(
        Wt, xT, o, 65536LL, 262144LL, 262144LL, 1024);

    norm_kernel<<<dim3(4096), 256, 0, stream>>>(o, xB, gamma, y);
}